// Round 4
// baseline (2932.886 us; speedup 1.0000x reference)
//
#include <hip/hip_runtime.h>
#include <hip/hip_bf16.h>
#include <stdint.h>

// EncoderLayer, MI355X. B=8 L=1024 DM=512 H=8 DK=64 DV=512.
// Round 4: all-f32 VALU anchor build. No MFMA, no global_load_lds, no dtype
// conversion pass. Only V/O/G buffers stored bf16 (workspace budget).
// Pipeline: lengths -> Qproj -> Kproj -> Vproj(->Vt bf16) ->
//           per-head { S=QK^T/8 f32 + softmax -> P f32 ; PV -> O bf16 } ->
//           gate GEMM (-> G bf16) -> head-softmax combine (f32) ->
//           FC + bias + residual + pad-mask -> f32 out.

using bf16 = __hip_bfloat16;
typedef float f32x4 __attribute__((ext_vector_type(4)));
typedef short s16x4 __attribute__((ext_vector_type(4)));
typedef short s16x8 __attribute__((ext_vector_type(8)));

#define DEV static __device__ __forceinline__

DEV float us2f(unsigned short u) { union { uint32_t i; float f; } x; x.i = ((uint32_t)u) << 16; return x.f; }
DEV float s2f(short s) { return us2f((unsigned short)s); }
DEV unsigned short f2bfu(float x) { return __builtin_bit_cast(unsigned short, __float2bfloat16(x)); }
DEV float bf2f(bf16 x) { return __bfloat162float(x); }

// ---------------- lengths extraction (robust to u8/i32/f32 mask encodings) ------------
__global__ void k_lengths(const unsigned char* __restrict__ mask, int* __restrict__ lens)
{
    __shared__ int flags[2];
    __shared__ int cnt[8];
    const int t = threadIdx.x;  // 256 threads
    if (t < 2) flags[t] = 0;
    if (t < 8) cnt[t] = 0;
    __syncthreads();
    int f0 = 0, f1 = 0;
    for (int i = t; i < 8192; i += 256) {
        unsigned char v = mask[i];
        if ((i & 3) != 0 && v != 0) f0 = 1;
        if ((i & 3) == 3 && v == 0x3F) f1 = 1;   // f32 1.0f high byte
    }
    if (f0) atomicOr(&flags[0], 1);
    if (f1) atomicOr(&flags[1], 1);
    __syncthreads();
    const int mode = flags[1] ? 2 : (flags[0] ? 0 : 1); // 0=u8, 1=i32, 2=f32
    const int b = t >> 5, lane32 = t & 31;
    int padc = 0;
    for (int j = lane32; j < 1024; j += 32) {
        const int idx = b * 1024 + j;
        bool pad;
        if (mode == 0)      pad = mask[idx] != 0;
        else if (mode == 1) pad = ((const int*)mask)[idx] != 0;
        else                pad = ((const float*)mask)[idx] != 0.0f;
        padc += pad ? 1 : 0;
    }
    atomicAdd(&cnt[b], padc);
    __syncthreads();
    if (t < 8) {
        const int len = 1024 - cnt[t];
        lens[t] = len;                     // actual length
        lens[8 + t] = (len + 31) >> 5;     // 32-granular steps (P zero-pad)
        lens[16 + t] = (len + 7) >> 3;     // 8-granular K-steps (PV BK=8)
    }
}

// ---------------- f32 SGEMM template: C = A * B^T, 128x128 tile, 8x8/thread -----------
// MODE 0: Q/K proj (A=enc f32 8192x512, Bt=w f32 512x512) -> scatter f32 [h][b][l][dk]+bias
// MODE 1: V proj   (A=enc f32, Bt=wv f32 4096x512) -> Vt bf16 [h][b][dv][l] + bias
// MODE 2: PV       (z=batch: A=P_z f32 1024x1024, Bt=Vt_(aux,z) bf16, nk len-capped)
//                  -> O bf16 [aux][z][l][dv]
// MODE 3: gate     (z=head: A=O_z bf16 8192x512, Bt=wg_z f32) -> G bf16 + bias
// MODE 4: fc       (A=comb f32 8192x512, Bt=wfc f32) -> f32 out + bias + resid + mask
template<int MODE>
__launch_bounds__(256)
__global__ void sgemm(const void* __restrict__ Abase, const void* __restrict__ Bbase,
                      void* __restrict__ Cbase, const float* __restrict__ bias,
                      const float* __restrict__ resid, const int* __restrict__ lens,
                      int ntn, int aux)
{
    constexpr bool ABF = (MODE == 3);   // A is bf16
    constexpr bool BBF = (MODE == 2);   // B is bf16
    __shared__ float sA[8 * 132];
    __shared__ float sB[8 * 132];

    const int bx = blockIdx.x, z = blockIdx.y;
    const int mt = bx / ntn, nt = bx % ntn;
    const int m0 = mt * 128, n0 = nt * 128;
    const int tid = threadIdx.x;
    const int tx = tid & 15, ty = tid >> 4;

    const char* A = (const char*)Abase;
    const char* Bt = (const char*)Bbase;
    int lda = 512, ldb = 512, nkb = 64;
    if (MODE == 2) {
        A  += (size_t)z * 1048576 * 4;   // P_z (f32 1024x1024)
        Bt += (size_t)z * 524288 * 2;    // Vt_(aux,z) (bf16 512x1024)
        lda = 1024; ldb = 1024;
        nkb = lens[16 + z];
    }
    if (MODE == 3) {
        A  += (size_t)z * 4194304 * 2;   // O_z (bf16 8192x512)
        Bt += (size_t)z * 262144 * 4;    // wg_z (f32 512x512)
    }

    float acc[8][8];
    #pragma unroll
    for (int i = 0; i < 8; ++i)
        #pragma unroll
        for (int j = 0; j < 8; ++j) acc[i][j] = 0.f;

    for (int kt = 0; kt < nkb; ++kt) {
        const int kb = kt * 8;
        __syncthreads();
        {   // stage A tile (128 x 8) transposed -> sA[k][m]
            const int r = tid >> 1, c0 = (tid & 1) * 4;
            float tmp[4];
            if (ABF) {
                const s16x4 v = *(const s16x4*)(A + ((size_t)(m0 + r) * lda + kb + c0) * 2);
                tmp[0] = s2f(v[0]); tmp[1] = s2f(v[1]); tmp[2] = s2f(v[2]); tmp[3] = s2f(v[3]);
            } else {
                const f32x4 v = *(const f32x4*)(A + ((size_t)(m0 + r) * lda + kb + c0) * 4);
                tmp[0] = v[0]; tmp[1] = v[1]; tmp[2] = v[2]; tmp[3] = v[3];
            }
            #pragma unroll
            for (int j = 0; j < 4; ++j) sA[(c0 + j) * 132 + r] = tmp[j];
        }
        {   // stage B tile (128 x 8) transposed -> sB[k][n]
            const int r = tid >> 1, c0 = (tid & 1) * 4;
            float tmp[4];
            if (BBF) {
                const s16x4 v = *(const s16x4*)(Bt + ((size_t)(n0 + r) * ldb + kb + c0) * 2);
                tmp[0] = s2f(v[0]); tmp[1] = s2f(v[1]); tmp[2] = s2f(v[2]); tmp[3] = s2f(v[3]);
            } else {
                const f32x4 v = *(const f32x4*)(Bt + ((size_t)(n0 + r) * ldb + kb + c0) * 4);
                tmp[0] = v[0]; tmp[1] = v[1]; tmp[2] = v[2]; tmp[3] = v[3];
            }
            #pragma unroll
            for (int j = 0; j < 4; ++j) sB[(c0 + j) * 132 + r] = tmp[j];
        }
        __syncthreads();
        #pragma unroll
        for (int k = 0; k < 8; ++k) {
            const f32x4 a0 = *(const f32x4*)&sA[k * 132 + ty * 8];
            const f32x4 a1 = *(const f32x4*)&sA[k * 132 + ty * 8 + 4];
            const f32x4 b0 = *(const f32x4*)&sB[k * 132 + tx * 8];
            const f32x4 b1 = *(const f32x4*)&sB[k * 132 + tx * 8 + 4];
            const float av[8] = {a0[0], a0[1], a0[2], a0[3], a1[0], a1[1], a1[2], a1[3]};
            const float bw[8] = {b0[0], b0[1], b0[2], b0[3], b1[0], b1[1], b1[2], b1[3]};
            #pragma unroll
            for (int i = 0; i < 8; ++i)
                #pragma unroll
                for (int j = 0; j < 8; ++j)
                    acc[i][j] += av[i] * bw[j];
        }
    }

    const int gmb = m0 + ty * 8, gnb = n0 + tx * 8;

    if constexpr (MODE == 0) {          // Q/K scatter, f32 out
        float* Q = (float*)Cbase;
        const int b = gmb >> 10;
        #pragma unroll
        for (int i = 0; i < 8; ++i) {
            const int l = (gmb + i) & 1023;
            #pragma unroll
            for (int jj = 0; jj < 2; ++jj) {
                const int gn = gnb + jj * 4;
                const int h = gn >> 6, dk = gn & 63;
                f32x4 v;
                #pragma unroll
                for (int j2 = 0; j2 < 4; ++j2) v[j2] = acc[i][jj * 4 + j2] + bias[gn + j2];
                *(f32x4*)&Q[(((size_t)(h * 8 + b)) * 1024 + l) * 64 + dk] = v;
            }
        }
    } else if constexpr (MODE == 1) {   // Vt scatter, bf16
        bf16* Vt = (bf16*)Cbase;
        const int b = gmb >> 10, l0 = gmb & 1023;
        #pragma unroll
        for (int j = 0; j < 8; ++j) {
            const int gn = gnb + j;
            const int h = gn >> 9, dv = gn & 511;
            const float bv = bias[gn];
            bf16* p = Vt + ((size_t)(h * 8 + b) * 512 + dv) * 1024 + l0;
            ushort4 lo, hi;
            lo.x = f2bfu(acc[0][j] + bv); lo.y = f2bfu(acc[1][j] + bv);
            lo.z = f2bfu(acc[2][j] + bv); lo.w = f2bfu(acc[3][j] + bv);
            hi.x = f2bfu(acc[4][j] + bv); hi.y = f2bfu(acc[5][j] + bv);
            hi.z = f2bfu(acc[6][j] + bv); hi.w = f2bfu(acc[7][j] + bv);
            *(ushort4*)p = lo;
            *(ushort4*)(p + 4) = hi;
        }
    } else if constexpr (MODE == 2) {   // O write, bf16 row-major
        bf16* O = (bf16*)Cbase + (size_t)(aux * 8 + z) * 524288;
        #pragma unroll
        for (int i = 0; i < 8; ++i) {
            const int gm = gmb + i;
            ushort4 lo, hi;
            lo.x = f2bfu(acc[i][0]); lo.y = f2bfu(acc[i][1]);
            lo.z = f2bfu(acc[i][2]); lo.w = f2bfu(acc[i][3]);
            hi.x = f2bfu(acc[i][4]); hi.y = f2bfu(acc[i][5]);
            hi.z = f2bfu(acc[i][6]); hi.w = f2bfu(acc[i][7]);
            bf16* p = O + (size_t)gm * 512 + gnb;
            *(ushort4*)p = lo;
            *(ushort4*)(p + 4) = hi;
        }
    } else if constexpr (MODE == 3) {   // G write, bf16 + bias
        bf16* G = (bf16*)Cbase + (size_t)z * 4194304;
        #pragma unroll
        for (int i = 0; i < 8; ++i) {
            const int gm = gmb + i;
            ushort4 lo, hi;
            lo.x = f2bfu(acc[i][0] + bias[z * 512 + gnb + 0]);
            lo.y = f2bfu(acc[i][1] + bias[z * 512 + gnb + 1]);
            lo.z = f2bfu(acc[i][2] + bias[z * 512 + gnb + 2]);
            lo.w = f2bfu(acc[i][3] + bias[z * 512 + gnb + 3]);
            hi.x = f2bfu(acc[i][4] + bias[z * 512 + gnb + 4]);
            hi.y = f2bfu(acc[i][5] + bias[z * 512 + gnb + 5]);
            hi.z = f2bfu(acc[i][6] + bias[z * 512 + gnb + 6]);
            hi.w = f2bfu(acc[i][7] + bias[z * 512 + gnb + 7]);
            bf16* p = G + (size_t)gm * 512 + gnb;
            *(ushort4*)p = lo;
            *(ushort4*)(p + 4) = hi;
        }
    } else {                            // FC: f32 out + bias + resid + pad-mask
        float* Out = (float*)Cbase;
        const int b = gmb >> 10;
        const int len = lens[b];
        #pragma unroll
        for (int i = 0; i < 8; ++i) {
            const int gm = gmb + i;
            const bool dead = (gm & 1023) >= len;
            #pragma unroll
            for (int jj = 0; jj < 2; ++jj) {
                const int gn = gnb + jj * 4;
                f32x4 v;
                #pragma unroll
                for (int j2 = 0; j2 < 4; ++j2)
                    v[j2] = dead ? 0.f
                                 : acc[i][jj * 4 + j2] + bias[gn + j2]
                                   + resid[(size_t)gm * 512 + gn + j2];
                *(f32x4*)&Out[(size_t)gm * 512 + gn] = v;
            }
        }
    }
}

// ---------------- f32: S = QK^T/8, masked softmax, P f32 (zero-padded) -----------------
__launch_bounds__(256)
__global__ void k_sattn_f32(const float* __restrict__ Qf, const float* __restrict__ Kf,
                            float* __restrict__ P, const int* __restrict__ lens, int head)
{
    __shared__ float S[32 * 1024];   // 128 KB
    __shared__ float sQ[32 * 68];
    __shared__ float sK[64 * 68];
    const int qb = blockIdx.x, z = blockIdx.y;      // z = batch
    const int hb = head * 8 + z;
    const int tid = threadIdx.x;

    {   // stage Q tile (32 x 64 f32)
        const int r = tid >> 3, d0 = (tid & 7) * 8;
        const float* src = &Qf[((size_t)hb * 1024 + (size_t)qb * 32 + r) * 64 + d0];
        *(f32x4*)&sQ[r * 68 + d0]     = *(const f32x4*)src;
        *(f32x4*)&sQ[r * 68 + d0 + 4] = *(const f32x4*)(src + 4);
    }

    const int k = tid & 63, qg = tid >> 6;
    for (int kc = 0; kc < 16; ++kc) {
        __syncthreads();             // protect sK overwrite (and first-iter sQ)
        {   // stage K chunk (64 x 64 f32)
            const int r = tid >> 2, c0 = (tid & 3) * 16;
            const float* src = &Kf[((size_t)hb * 1024 + (size_t)kc * 64 + r) * 64 + c0];
            #pragma unroll
            for (int c = 0; c < 4; ++c)
                *(f32x4*)&sK[r * 68 + c0 + c * 4] = *(const f32x4*)(src + c * 4);
        }
        __syncthreads();
        #pragma unroll
        for (int i = 0; i < 8; ++i) {
            const int q = qg + i * 4;
            float acc = 0.f;
            #pragma unroll
            for (int dj = 0; dj < 16; ++dj) {
                const f32x4 kv = *(const f32x4*)&sK[k * 68 + dj * 4];
                const f32x4 qv = *(const f32x4*)&sQ[q * 68 + dj * 4];
                acc += qv[0] * kv[0] + qv[1] * kv[1] + qv[2] * kv[2] + qv[3] * kv[3];
            }
            S[q * 1024 + kc * 64 + k] = acc * 0.125f;
        }
    }
    __syncthreads();

    const int len = lens[z], lenpad = lens[8 + z] * 32;
    const int w = tid >> 6, lane = tid & 63;
    for (int rr = 0; rr < 8; ++rr) {
        const int row = w * 8 + rr;
        float* Sr = &S[row * 1024];
        float mx = -3.0e38f;
        for (int j = lane; j < len; j += 64) mx = fmaxf(mx, Sr[j]);
        #pragma unroll
        for (int off = 32; off; off >>= 1) mx = fmaxf(mx, __shfl_xor(mx, off));
        float sum = 0.f;
        for (int j = lane; j < len; j += 64) { const float e = __expf(Sr[j] - mx); Sr[j] = e; sum += e; }
        #pragma unroll
        for (int off = 32; off; off >>= 1) sum += __shfl_xor(sum, off);
        const float rinv = 1.0f / sum;
        float* Pr = P + ((size_t)z * 1024 + (size_t)qb * 32 + row) * 1024;
        for (int j = lane; j < lenpad; j += 64)
            Pr[j] = (j < len) ? Sr[j] * rinv : 0.f;
    }
}

// ---------------- head-softmax gate combine: comb = sum_h softmax_h(G) * O -------------
__launch_bounds__(512)
__global__ void k_combine_f32(const bf16* __restrict__ G, const bf16* __restrict__ O,
                              float* __restrict__ comb)
{
    const size_t row = blockIdx.x;
    const int e = threadIdx.x;
    const size_t idx = row * 512 + e;
    float g[8];
    #pragma unroll
    for (int h = 0; h < 8; ++h) g[h] = bf2f(G[(size_t)h * 4194304 + idx]);
    float mx = g[0];
    #pragma unroll
    for (int h = 1; h < 8; ++h) mx = fmaxf(mx, g[h]);
    float s = 0.f, c = 0.f;
    #pragma unroll
    for (int h = 0; h < 8; ++h) {
        const float p = __expf(g[h] - mx);
        s += p;
        c += p * bf2f(O[(size_t)h * 4194304 + idx]);
    }
    comb[idx] = c / s;
}

__global__ void k_sentinel(float* out, int n) {
    const int i = blockIdx.x * 256 + threadIdx.x;
    if (i < n) out[i] = 12345.0f;
}

// ---------------------------------------------------------------------------------------
extern "C" void kernel_launch(void* const* d_in, const int* in_sizes, int n_in,
                              void* d_out, int out_size, void* d_ws, size_t ws_size,
                              hipStream_t stream)
{
    const float* enc = (const float*)d_in[0];
    const unsigned char* npm = (const unsigned char*)d_in[1];
    const float* wq  = (const float*)d_in[3];
    const float* bq  = (const float*)d_in[4];
    const float* wk  = (const float*)d_in[5];
    const float* bk  = (const float*)d_in[6];
    const float* wv  = (const float*)d_in[7];
    const float* bv  = (const float*)d_in[8];
    const float* wg  = (const float*)d_in[9];
    const float* bg  = (const float*)d_in[10];
    const float* wfc = (const float*)d_in[11];
    const float* bfc = (const float*)d_in[12];

    char* ws = (char*)d_ws;
    size_t o = 0;
    auto take = [&](size_t bytes) { char* p = ws + o; o += (bytes + 255) & ~(size_t)255; return p; };
    int*   lens = (int*)take(128);
    float* Qf   = (float*)take((size_t)4194304 * 4);   // [h][b][l][dk] f32
    float* Kf   = (float*)take((size_t)4194304 * 4);   // [h][b][l][dk] f32
    bf16*  Vt   = (bf16*)take((size_t)33554432 * 2);   // [h][b][dv][l] bf16; reused as G
    bf16*  Ob   = (bf16*)take((size_t)33554432 * 2);   // [h][b][l][dv] bf16
    float* Pf   = (float*)take((size_t)8388608 * 4);   // one head: [b][q][k] f32
    float* comb = (float*)take((size_t)4194304 * 4);   // [b,l][dv] f32
    bf16*  Gb   = Vt;

    if (ws_size < o) {
        k_sentinel<<<dim3((out_size + 255) / 256), 256, 0, stream>>>((float*)d_out, out_size);
        return;
    }

    k_lengths<<<1, 256, 0, stream>>>(npm, lens);

    // Q, K, V projections
    sgemm<0><<<dim3(64 * 4, 1), 256, 0, stream>>>(enc, wq, Qf, bq, nullptr, lens, 4, 0);
    sgemm<0><<<dim3(64 * 4, 1), 256, 0, stream>>>(enc, wk, Kf, bk, nullptr, lens, 4, 0);
    sgemm<1><<<dim3(64 * 32, 1), 256, 0, stream>>>(enc, wv, Vt, bv, nullptr, lens, 32, 0);

    // attention per head: f32 S+softmax -> P, then PV -> O
    for (int g = 0; g < 8; ++g) {
        k_sattn_f32<<<dim3(32, 8), 256, 0, stream>>>(Qf, Kf, Pf, lens, g);
        sgemm<2><<<dim3(8 * 4, 8), 256, 0, stream>>>(Pf, Vt + (size_t)g * 4194304, Ob,
                                                     nullptr, nullptr, lens, 4, g);
    }

    // gate GEMM per head
    sgemm<3><<<dim3(64 * 4, 8), 256, 0, stream>>>(Ob, wg, Gb, bg, nullptr, lens, 4, 0);

    // head softmax + weighted combine
    k_combine_f32<<<dim3(8192), 512, 0, stream>>>(Gb, Ob, comb);

    // FC + bias + residual + pad-mask -> f32 out
    sgemm<4><<<dim3(64 * 4, 1), 256, 0, stream>>>(comb, wfc, d_out, bfc, enc, lens, 4, 0);
}

// Round 5
// 1365.860 us; speedup vs baseline: 2.1473x; 2.1473x over previous
//
#include <hip/hip_runtime.h>
#include <hip/hip_bf16.h>
#include <stdint.h>

// EncoderLayer, MI355X. B=8 L=1024 DM=512 H=8 DK=64 DV=512.
// Round 5: anchor pipeline (verified round 4) with the five GEMM stages moved
// to MFMA via split-bf16 (hi/lo) 3-term arithmetic. k_sattn / k_combine /
// k_lengths byte-identical to the verified anchor.

using bf16 = __hip_bfloat16;
typedef float f32x4 __attribute__((ext_vector_type(4)));
typedef short s16x4 __attribute__((ext_vector_type(4)));
typedef short s16x8 __attribute__((ext_vector_type(8)));

#define DEV static __device__ __forceinline__

DEV float us2f(unsigned short u) { union { uint32_t i; float f; } x; x.i = ((uint32_t)u) << 16; return x.f; }
DEV float s2f(short s) { return us2f((unsigned short)s); }
DEV unsigned short f2bfu(float x) { return __builtin_bit_cast(unsigned short, __float2bfloat16(x)); }
DEV float bf2f(bf16 x) { return __bfloat162float(x); }
DEV bf16 f2bf(float x) { return __float2bfloat16(x); }

// D = A(16x32)*B(32x16)+C. A: lane l holds A[l&15][8*(l>>4)+j]; B: lane l holds
// B[8*(l>>4)+j][l&15]; C/D: col=lane&15, row=4*(lane>>4)+reg (m89-verified).
DEV void mfma_bf16(f32x4& c, s16x8 a, s16x8 b) {
    asm("v_mfma_f32_16x16x32_bf16 %0, %1, %2, %0" : "+v"(c) : "v"(a), "v"(b));
}

// split 8 consecutive f32 into bf16 hi + lo
DEV void cvt8(const float* p, s16x8& h, s16x8& l) {
    #pragma unroll
    for (int j = 0; j < 8; ++j) {
        const float v = p[j];
        const unsigned short hu = f2bfu(v);
        h[j] = (short)hu;
        l[j] = (short)f2bfu(v - us2f(hu));
    }
}
DEV void cvt8hi(const float* p, s16x8& h) {
    #pragma unroll
    for (int j = 0; j < 8; ++j) h[j] = (short)f2bfu(p[j]);
}

// ---------------- lengths extraction (robust to u8/i32/f32 mask encodings) ------------
__global__ void k_lengths(const unsigned char* __restrict__ mask, int* __restrict__ lens)
{
    __shared__ int flags[2];
    __shared__ int cnt[8];
    const int t = threadIdx.x;  // 256 threads
    if (t < 2) flags[t] = 0;
    if (t < 8) cnt[t] = 0;
    __syncthreads();
    int f0 = 0, f1 = 0;
    for (int i = t; i < 8192; i += 256) {
        unsigned char v = mask[i];
        if ((i & 3) != 0 && v != 0) f0 = 1;
        if ((i & 3) == 3 && v == 0x3F) f1 = 1;   // f32 1.0f high byte
    }
    if (f0) atomicOr(&flags[0], 1);
    if (f1) atomicOr(&flags[1], 1);
    __syncthreads();
    const int mode = flags[1] ? 2 : (flags[0] ? 0 : 1); // 0=u8, 1=i32, 2=f32
    const int b = t >> 5, lane32 = t & 31;
    int padc = 0;
    for (int j = lane32; j < 1024; j += 32) {
        const int idx = b * 1024 + j;
        bool pad;
        if (mode == 0)      pad = mask[idx] != 0;
        else if (mode == 1) pad = ((const int*)mask)[idx] != 0;
        else                pad = ((const float*)mask)[idx] != 0.0f;
        padc += pad ? 1 : 0;
    }
    atomicAdd(&cnt[b], padc);
    __syncthreads();
    if (t < 8) {
        const int len = 1024 - cnt[t];
        lens[t] = len;                     // actual length
        lens[8 + t] = (len + 31) >> 5;     // 32-granular steps
        lens[16 + t] = (len + 7) >> 3;
    }
}

// ---------------- unified MFMA GEMM: C = A * B^T, 128x128 tile, BK=32 ------------------
// MODE 0: Q/K proj (A=enc f32, Bt=w f32 [512][512]) -> f32 scatter [h][b][l][dk] + bias
// MODE 1: V proj   (A=enc f32, Bt=wv f32 [4096][512]) -> Vt bf16 [h][b][dv][l] + bias
// MODE 2: PV       (z=batch: A=P_z f32 [1024][1024], Bt=Vt_(aux,z) bf16, nk len-capped)
//                  -> O bf16 [aux][z][l][dv]
// MODE 3: gate     (z=head: A=O_z bf16, Bt=wg_z f32) -> G bf16 + bias
// MODE 4: fc       (A=comb f32, Bt=wfc f32) -> f32 out + bias + resid + pad-mask
template<int MODE>
__launch_bounds__(256)
__global__ void mgemm(const void* __restrict__ Abase, const void* __restrict__ Bbase,
                      void* __restrict__ Cbase, const float* __restrict__ bias,
                      const float* __restrict__ resid, const int* __restrict__ lens,
                      int ntn, int aux)
{
    constexpr bool A_BF = (MODE == 3);                      // A is bf16-native
    constexpr bool B_BF = (MODE == 2);                      // B is bf16-native
    constexpr bool A_SP = (MODE == 0 || MODE == 1 || MODE == 4);  // split A (hi+lo)
    constexpr bool B_SP = !B_BF;                            // split B (hi+lo)
    constexpr int LS = 40;                                  // LDS row stride (elems)

    __shared__ bf16 sAh[128 * LS];
    __shared__ bf16 sAl[A_SP ? 128 * LS : 8];
    __shared__ bf16 sBh[128 * LS];
    __shared__ bf16 sBl[B_SP ? 128 * LS : 8];

    const int bx = blockIdx.x, z = blockIdx.y;
    const int mt = bx / ntn, nt = bx % ntn;
    const int m0 = mt * 128, n0 = nt * 128;
    const int tid = threadIdx.x;
    const int lane = tid & 63, w = tid >> 6;
    const int l16 = lane & 15, l4 = lane >> 4;
    const int wm = w >> 1, wn = w & 1;

    const char* A = (const char*)Abase;
    const char* Bt = (const char*)Bbase;
    int lda = 512, ldb = 512, nkb = 16;
    if (MODE == 2) {
        A  += (size_t)z * 1048576 * 4;   // P_z (f32 1024x1024)
        Bt += (size_t)z * 524288 * 2;    // Vt_(aux,z) (bf16 512x1024)
        lda = 1024; ldb = 1024;
        nkb = lens[8 + z];
    }
    if (MODE == 3) {
        A  += (size_t)z * 4194304 * 2;   // O_z (bf16 8192x512)
        Bt += (size_t)z * 262144 * 4;    // wg_z (f32 512x512)
    }

    f32x4 acc[4][4];
    #pragma unroll
    for (int i = 0; i < 4; ++i)
        #pragma unroll
        for (int j = 0; j < 4; ++j) acc[i][j] = (f32x4){0.f, 0.f, 0.f, 0.f};

    const int sr = tid >> 1, sc = (tid & 1) * 16;   // staging: row, col-half

    for (int kt = 0; kt < nkb; ++kt) {
        const int kb = kt * 32;
        __syncthreads();
        // ---- stage A tile (128 x 32) ----
        if constexpr (A_BF) {
            const bf16* p = (const bf16*)A + (size_t)(m0 + sr) * lda + kb + sc;
            *(s16x8*)&sAh[sr * LS + sc]     = *(const s16x8*)p;
            *(s16x8*)&sAh[sr * LS + sc + 8] = *(const s16x8*)(p + 8);
        } else {
            const float* p = (const float*)A + (size_t)(m0 + sr) * lda + kb + sc;
            s16x8 h0, h1;
            if constexpr (A_SP) {
                s16x8 l0, l1;
                cvt8(p, h0, l0); cvt8(p + 8, h1, l1);
                *(s16x8*)&sAl[sr * LS + sc]     = l0;
                *(s16x8*)&sAl[sr * LS + sc + 8] = l1;
            } else {
                cvt8hi(p, h0); cvt8hi(p + 8, h1);
            }
            *(s16x8*)&sAh[sr * LS + sc]     = h0;
            *(s16x8*)&sAh[sr * LS + sc + 8] = h1;
        }
        // ---- stage B tile (128 x 32) ----
        if constexpr (B_BF) {
            const bf16* p = (const bf16*)Bt + (size_t)(n0 + sr) * ldb + kb + sc;
            *(s16x8*)&sBh[sr * LS + sc]     = *(const s16x8*)p;
            *(s16x8*)&sBh[sr * LS + sc + 8] = *(const s16x8*)(p + 8);
        } else {
            const float* p = (const float*)Bt + (size_t)(n0 + sr) * ldb + kb + sc;
            s16x8 h0, h1, l0, l1;
            cvt8(p, h0, l0); cvt8(p + 8, h1, l1);
            *(s16x8*)&sBh[sr * LS + sc]     = h0;
            *(s16x8*)&sBh[sr * LS + sc + 8] = h1;
            *(s16x8*)&sBl[sr * LS + sc]     = l0;
            *(s16x8*)&sBl[sr * LS + sc + 8] = l1;
        }
        __syncthreads();

        // ---- fragments + MFMA ----
        s16x8 ah[4], al[4], bh[4], bl[4];
        #pragma unroll
        for (int i = 0; i < 4; ++i) {
            const int ra = (wm * 64 + i * 16 + l16) * LS + l4 * 8;
            const int rb = (wn * 64 + i * 16 + l16) * LS + l4 * 8;
            ah[i] = *(const s16x8*)&sAh[ra];
            if constexpr (A_SP) al[i] = *(const s16x8*)&sAl[ra];
            bh[i] = *(const s16x8*)&sBh[rb];
            if constexpr (B_SP) bl[i] = *(const s16x8*)&sBl[rb];
        }
        #pragma unroll
        for (int mi = 0; mi < 4; ++mi)
            #pragma unroll
            for (int ni = 0; ni < 4; ++ni) {
                mfma_bf16(acc[mi][ni], ah[mi], bh[ni]);
                if constexpr (B_SP) mfma_bf16(acc[mi][ni], ah[mi], bl[ni]);
                if constexpr (A_SP) mfma_bf16(acc[mi][ni], al[mi], bh[ni]);
            }
    }

    // ---- epilogues (C frag: row = 4*l4 + r, col = l16) ----
    if constexpr (MODE == 0) {
        float* Q = (float*)Cbase;
        #pragma unroll
        for (int ni = 0; ni < 4; ++ni) {
            const int gn = n0 + wn * 64 + ni * 16 + l16;
            const float bs = bias[gn];
            const int h = gn >> 6, dk = gn & 63;
            #pragma unroll
            for (int mi = 0; mi < 4; ++mi) {
                const int gm0 = m0 + wm * 64 + mi * 16 + l4 * 4;
                const int b = gm0 >> 10, l0 = gm0 & 1023;
                float* dst = Q + (((size_t)(h * 8 + b)) * 1024 + l0) * 64 + dk;
                #pragma unroll
                for (int r = 0; r < 4; ++r) dst[(size_t)r * 64] = acc[mi][ni][r] + bs;
            }
        }
    } else if constexpr (MODE == 1) {
        bf16* Vt = (bf16*)Cbase;
        #pragma unroll
        for (int ni = 0; ni < 4; ++ni) {
            const int gn = n0 + wn * 64 + ni * 16 + l16;
            const float bs = bias[gn];
            const int h = gn >> 9, dv = gn & 511;
            #pragma unroll
            for (int mi = 0; mi < 4; ++mi) {
                const int gm0 = m0 + wm * 64 + mi * 16 + l4 * 4;
                const int b = gm0 >> 10, l0 = gm0 & 1023;
                ushort4 t;
                t.x = f2bfu(acc[mi][ni][0] + bs);
                t.y = f2bfu(acc[mi][ni][1] + bs);
                t.z = f2bfu(acc[mi][ni][2] + bs);
                t.w = f2bfu(acc[mi][ni][3] + bs);
                *(ushort4*)(Vt + ((size_t)(h * 8 + b) * 512 + dv) * 1024 + l0) = t;
            }
        }
    } else if constexpr (MODE == 2) {
        bf16* O = (bf16*)Cbase + (size_t)(aux * 8 + z) * 524288;
        #pragma unroll
        for (int mi = 0; mi < 4; ++mi) {
            const int gm0 = m0 + wm * 64 + mi * 16 + l4 * 4;
            #pragma unroll
            for (int ni = 0; ni < 4; ++ni) {
                const int gn = n0 + wn * 64 + ni * 16 + l16;
                #pragma unroll
                for (int r = 0; r < 4; ++r)
                    O[(size_t)(gm0 + r) * 512 + gn] = f2bf(acc[mi][ni][r]);
            }
        }
    } else if constexpr (MODE == 3) {
        bf16* G = (bf16*)Cbase + (size_t)z * 4194304;
        #pragma unroll
        for (int ni = 0; ni < 4; ++ni) {
            const int gn = n0 + wn * 64 + ni * 16 + l16;
            const float bs = bias[z * 512 + gn];
            #pragma unroll
            for (int mi = 0; mi < 4; ++mi) {
                const int gm0 = m0 + wm * 64 + mi * 16 + l4 * 4;
                #pragma unroll
                for (int r = 0; r < 4; ++r)
                    G[(size_t)(gm0 + r) * 512 + gn] = f2bf(acc[mi][ni][r] + bs);
            }
        }
    } else {
        float* Out = (float*)Cbase;
        #pragma unroll
        for (int mi = 0; mi < 4; ++mi) {
            const int gm0 = m0 + wm * 64 + mi * 16 + l4 * 4;
            const int len = lens[gm0 >> 10];
            #pragma unroll
            for (int ni = 0; ni < 4; ++ni) {
                const int gn = n0 + wn * 64 + ni * 16 + l16;
                const float bs = bias[gn];
                #pragma unroll
                for (int r = 0; r < 4; ++r) {
                    const int gm = gm0 + r;
                    const bool dead = (gm & 1023) >= len;
                    Out[(size_t)gm * 512 + gn] =
                        dead ? 0.f : acc[mi][ni][r] + bs + resid[(size_t)gm * 512 + gn];
                }
            }
        }
    }
}

// ---------------- f32: S = QK^T/8, masked softmax, P f32 (zero-padded) -----------------
// (byte-identical to the verified round-4 anchor)
__launch_bounds__(256)
__global__ void k_sattn_f32(const float* __restrict__ Qf, const float* __restrict__ Kf,
                            float* __restrict__ P, const int* __restrict__ lens, int head)
{
    __shared__ float S[32 * 1024];   // 128 KB
    __shared__ float sQ[32 * 68];
    __shared__ float sK[64 * 68];
    const int qb = blockIdx.x, z = blockIdx.y;      // z = batch
    const int hb = head * 8 + z;
    const int tid = threadIdx.x;

    {   // stage Q tile (32 x 64 f32)
        const int r = tid >> 3, d0 = (tid & 7) * 8;
        const float* src = &Qf[((size_t)hb * 1024 + (size_t)qb * 32 + r) * 64 + d0];
        *(f32x4*)&sQ[r * 68 + d0]     = *(const f32x4*)src;
        *(f32x4*)&sQ[r * 68 + d0 + 4] = *(const f32x4*)(src + 4);
    }

    const int k = tid & 63, qg = tid >> 6;
    for (int kc = 0; kc < 16; ++kc) {
        __syncthreads();             // protect sK overwrite (and first-iter sQ)
        {   // stage K chunk (64 x 64 f32)
            const int r = tid >> 2, c0 = (tid & 3) * 16;
            const float* src = &Kf[((size_t)hb * 1024 + (size_t)kc * 64 + r) * 64 + c0];
            #pragma unroll
            for (int c = 0; c < 4; ++c)
                *(f32x4*)&sK[r * 68 + c0 + c * 4] = *(const f32x4*)(src + c * 4);
        }
        __syncthreads();
        #pragma unroll
        for (int i = 0; i < 8; ++i) {
            const int q = qg + i * 4;
            float acc = 0.f;
            #pragma unroll
            for (int dj = 0; dj < 16; ++dj) {
                const f32x4 kv = *(const f32x4*)&sK[k * 68 + dj * 4];
                const f32x4 qv = *(const f32x4*)&sQ[q * 68 + dj * 4];
                acc += qv[0] * kv[0] + qv[1] * kv[1] + qv[2] * kv[2] + qv[3] * kv[3];
            }
            S[q * 1024 + kc * 64 + k] = acc * 0.125f;
        }
    }
    __syncthreads();

    const int len = lens[z], lenpad = lens[8 + z] * 32;
    const int w = tid >> 6, lane = tid & 63;
    for (int rr = 0; rr < 8; ++rr) {
        const int row = w * 8 + rr;
        float* Sr = &S[row * 1024];
        float mx = -3.0e38f;
        for (int j = lane; j < len; j += 64) mx = fmaxf(mx, Sr[j]);
        #pragma unroll
        for (int off = 32; off; off >>= 1) mx = fmaxf(mx, __shfl_xor(mx, off));
        float sum = 0.f;
        for (int j = lane; j < len; j += 64) { const float e = __expf(Sr[j] - mx); Sr[j] = e; sum += e; }
        #pragma unroll
        for (int off = 32; off; off >>= 1) sum += __shfl_xor(sum, off);
        const float rinv = 1.0f / sum;
        float* Pr = P + ((size_t)z * 1024 + (size_t)qb * 32 + row) * 1024;
        for (int j = lane; j < lenpad; j += 64)
            Pr[j] = (j < len) ? Sr[j] * rinv : 0.f;
    }
}

// ---------------- head-softmax gate combine: comb = sum_h softmax_h(G) * O -------------
__launch_bounds__(512)
__global__ void k_combine_f32(const bf16* __restrict__ G, const bf16* __restrict__ O,
                              float* __restrict__ comb)
{
    const size_t row = blockIdx.x;
    const int e = threadIdx.x;
    const size_t idx = row * 512 + e;
    float g[8];
    #pragma unroll
    for (int h = 0; h < 8; ++h) g[h] = bf2f(G[(size_t)h * 4194304 + idx]);
    float mx = g[0];
    #pragma unroll
    for (int h = 1; h < 8; ++h) mx = fmaxf(mx, g[h]);
    float s = 0.f, c = 0.f;
    #pragma unroll
    for (int h = 0; h < 8; ++h) {
        const float p = __expf(g[h] - mx);
        s += p;
        c += p * bf2f(O[(size_t)h * 4194304 + idx]);
    }
    comb[idx] = c / s;
}

__global__ void k_sentinel(float* out, int n) {
    const int i = blockIdx.x * 256 + threadIdx.x;
    if (i < n) out[i] = 12345.0f;
}

// ---------------------------------------------------------------------------------------
extern "C" void kernel_launch(void* const* d_in, const int* in_sizes, int n_in,
                              void* d_out, int out_size, void* d_ws, size_t ws_size,
                              hipStream_t stream)
{
    const float* enc = (const float*)d_in[0];
    const unsigned char* npm = (const unsigned char*)d_in[1];
    const float* wq  = (const float*)d_in[3];
    const float* bq  = (const float*)d_in[4];
    const float* wk  = (const float*)d_in[5];
    const float* bk  = (const float*)d_in[6];
    const float* wv  = (const float*)d_in[7];
    const float* bv  = (const float*)d_in[8];
    const float* wg  = (const float*)d_in[9];
    const float* bg  = (const float*)d_in[10];
    const float* wfc = (const float*)d_in[11];
    const float* bfc = (const float*)d_in[12];

    char* ws = (char*)d_ws;
    size_t o = 0;
    auto take = [&](size_t bytes) { char* p = ws + o; o += (bytes + 255) & ~(size_t)255; return p; };
    int*   lens = (int*)take(128);
    float* Qf   = (float*)take((size_t)4194304 * 4);   // [h][b][l][dk] f32
    float* Kf   = (float*)take((size_t)4194304 * 4);   // [h][b][l][dk] f32
    bf16*  Vt   = (bf16*)take((size_t)33554432 * 2);   // [h][b][dv][l] bf16; reused as G
    bf16*  Ob   = (bf16*)take((size_t)33554432 * 2);   // [h][b][l][dv] bf16
    float* Pf   = (float*)take((size_t)8388608 * 4);   // one head: [b][q][k] f32
    float* comb = (float*)take((size_t)4194304 * 4);   // [b,l][dv] f32
    bf16*  Gb   = Vt;

    if (ws_size < o) {
        k_sentinel<<<dim3((out_size + 255) / 256), 256, 0, stream>>>((float*)d_out, out_size);
        return;
    }

    k_lengths<<<1, 256, 0, stream>>>(npm, lens);

    // Q, K, V projections (MFMA, split-bf16 3-term)
    mgemm<0><<<dim3(64 * 4, 1), 256, 0, stream>>>(enc, wq, Qf, bq, nullptr, lens, 4, 0);
    mgemm<0><<<dim3(64 * 4, 1), 256, 0, stream>>>(enc, wk, Kf, bk, nullptr, lens, 4, 0);
    mgemm<1><<<dim3(64 * 32, 1), 256, 0, stream>>>(enc, wv, Vt, bv, nullptr, lens, 32, 0);

    // attention per head: f32 S+softmax -> P, then MFMA PV -> O
    for (int g = 0; g < 8; ++g) {
        k_sattn_f32<<<dim3(32, 8), 256, 0, stream>>>(Qf, Kf, Pf, lens, g);
        mgemm<2><<<dim3(8 * 4, 8), 256, 0, stream>>>(Pf, Vt + (size_t)g * 4194304, Ob,
                                                     nullptr, nullptr, lens, 4, g);
    }

    // gate GEMM per head (MFMA, A bf16-native, B split 2-term)
    mgemm<3><<<dim3(64 * 4, 8), 256, 0, stream>>>(Ob, wg, Gb, bg, nullptr, lens, 4, 0);

    // head softmax + weighted combine
    k_combine_f32<<<dim3(8192), 512, 0, stream>>>(Gb, Ob, comb);

    // FC + bias + residual + pad-mask -> f32 out
    mgemm<4><<<dim3(64 * 4, 1), 256, 0, stream>>>(comb, wfc, d_out, bfc, enc, lens, 4, 0);
}

// Round 7
// 1271.513 us; speedup vs baseline: 2.3066x; 1.0742x over previous
//
#include <hip/hip_runtime.h>
#include <hip/hip_bf16.h>
#include <stdint.h>

// EncoderLayer, MI355X. B=8 L=1024 DM=512 H=8 DK=64 DV=512.
// Round 7: round-5 passing base +
//  (1) k_sattn_f32 inner loop restructured: K-register reuse + dj-rotation
//      (kills the 8-way LDS bank conflict on sK reads), math unchanged.
//  (2) V projection 2-term split (error < Vt bf16 storage ulp).

using bf16 = __hip_bfloat16;
typedef float f32x4 __attribute__((ext_vector_type(4)));
typedef short s16x4 __attribute__((ext_vector_type(4)));
typedef short s16x8 __attribute__((ext_vector_type(8)));

#define DEV static __device__ __forceinline__

DEV float us2f(unsigned short u) { union { uint32_t i; float f; } x; x.i = ((uint32_t)u) << 16; return x.f; }
DEV float s2f(short s) { return us2f((unsigned short)s); }
DEV unsigned short f2bfu(float x) { return __builtin_bit_cast(unsigned short, __float2bfloat16(x)); }
DEV float bf2f(bf16 x) { return __bfloat162float(x); }
DEV bf16 f2bf(float x) { return __float2bfloat16(x); }

// D = A(16x32)*B(32x16)+C. A: lane l holds A[l&15][8*(l>>4)+j]; B: lane l holds
// B[8*(l>>4)+j][l&15]; C/D: col=lane&15, row=4*(lane>>4)+reg (m89-verified).
DEV void mfma_bf16(f32x4& c, s16x8 a, s16x8 b) {
    asm("v_mfma_f32_16x16x32_bf16 %0, %1, %2, %0" : "+v"(c) : "v"(a), "v"(b));
}

// split 8 consecutive f32 into bf16 hi + lo
DEV void cvt8(const float* p, s16x8& h, s16x8& l) {
    #pragma unroll
    for (int j = 0; j < 8; ++j) {
        const float v = p[j];
        const unsigned short hu = f2bfu(v);
        h[j] = (short)hu;
        l[j] = (short)f2bfu(v - us2f(hu));
    }
}
DEV void cvt8hi(const float* p, s16x8& h) {
    #pragma unroll
    for (int j = 0; j < 8; ++j) h[j] = (short)f2bfu(p[j]);
}

// ---------------- lengths extraction (robust to u8/i32/f32 mask encodings) ------------
__global__ void k_lengths(const unsigned char* __restrict__ mask, int* __restrict__ lens)
{
    __shared__ int flags[2];
    __shared__ int cnt[8];
    const int t = threadIdx.x;  // 256 threads
    if (t < 2) flags[t] = 0;
    if (t < 8) cnt[t] = 0;
    __syncthreads();
    int f0 = 0, f1 = 0;
    for (int i = t; i < 8192; i += 256) {
        unsigned char v = mask[i];
        if ((i & 3) != 0 && v != 0) f0 = 1;
        if ((i & 3) == 3 && v == 0x3F) f1 = 1;   // f32 1.0f high byte
    }
    if (f0) atomicOr(&flags[0], 1);
    if (f1) atomicOr(&flags[1], 1);
    __syncthreads();
    const int mode = flags[1] ? 2 : (flags[0] ? 0 : 1); // 0=u8, 1=i32, 2=f32
    const int b = t >> 5, lane32 = t & 31;
    int padc = 0;
    for (int j = lane32; j < 1024; j += 32) {
        const int idx = b * 1024 + j;
        bool pad;
        if (mode == 0)      pad = mask[idx] != 0;
        else if (mode == 1) pad = ((const int*)mask)[idx] != 0;
        else                pad = ((const float*)mask)[idx] != 0.0f;
        padc += pad ? 1 : 0;
    }
    atomicAdd(&cnt[b], padc);
    __syncthreads();
    if (t < 8) {
        const int len = 1024 - cnt[t];
        lens[t] = len;                     // actual length
        lens[8 + t] = (len + 31) >> 5;     // 32-granular steps
        lens[16 + t] = (len + 7) >> 3;
    }
}

// ---------------- unified MFMA GEMM: C = A * B^T, 128x128 tile, BK=32 ------------------
// MODE 0: Q/K proj (A=enc f32, Bt=w f32 [512][512]) -> f32 scatter [h][b][l][dk] + bias
// MODE 1: V proj   (A=enc f32 hi-only, Bt=wv f32 split) -> Vt bf16 [h][b][dv][l] + bias
// MODE 2: PV       (z=batch: A=P_z f32 [1024][1024], Bt=Vt_(aux,z) bf16, nk len-capped)
//                  -> O bf16 [aux][z][l][dv]
// MODE 3: gate     (z=head: A=O_z bf16, Bt=wg_z f32) -> G bf16 + bias
// MODE 4: fc       (A=comb f32, Bt=wfc f32) -> f32 out + bias + resid + pad-mask
template<int MODE>
__launch_bounds__(256)
__global__ void mgemm(const void* __restrict__ Abase, const void* __restrict__ Bbase,
                      void* __restrict__ Cbase, const float* __restrict__ bias,
                      const float* __restrict__ resid, const int* __restrict__ lens,
                      int ntn, int aux)
{
    constexpr bool A_BF = (MODE == 3);                      // A is bf16-native
    constexpr bool B_BF = (MODE == 2);                      // B is bf16-native
    constexpr bool A_SP = (MODE == 0 || MODE == 4);         // split A (hi+lo)
    constexpr bool B_SP = !B_BF;                            // split B (hi+lo)
    constexpr int LS = 40;                                  // LDS row stride (elems)

    __shared__ bf16 sAh[128 * LS];
    __shared__ bf16 sAl[A_SP ? 128 * LS : 8];
    __shared__ bf16 sBh[128 * LS];
    __shared__ bf16 sBl[B_SP ? 128 * LS : 8];

    const int bx = blockIdx.x, z = blockIdx.y;
    const int mt = bx / ntn, nt = bx % ntn;
    const int m0 = mt * 128, n0 = nt * 128;
    const int tid = threadIdx.x;
    const int lane = tid & 63, w = tid >> 6;
    const int l16 = lane & 15, l4 = lane >> 4;
    const int wm = w >> 1, wn = w & 1;

    const char* A = (const char*)Abase;
    const char* Bt = (const char*)Bbase;
    int lda = 512, ldb = 512, nkb = 16;
    if (MODE == 2) {
        A  += (size_t)z * 1048576 * 4;   // P_z (f32 1024x1024)
        Bt += (size_t)z * 524288 * 2;    // Vt_(aux,z) (bf16 512x1024)
        lda = 1024; ldb = 1024;
        nkb = lens[8 + z];
    }
    if (MODE == 3) {
        A  += (size_t)z * 4194304 * 2;   // O_z (bf16 8192x512)
        Bt += (size_t)z * 262144 * 4;    // wg_z (f32 512x512)
    }

    f32x4 acc[4][4];
    #pragma unroll
    for (int i = 0; i < 4; ++i)
        #pragma unroll
        for (int j = 0; j < 4; ++j) acc[i][j] = (f32x4){0.f, 0.f, 0.f, 0.f};

    const int sr = tid >> 1, sc = (tid & 1) * 16;   // staging: row, col-half

    for (int kt = 0; kt < nkb; ++kt) {
        const int kb = kt * 32;
        __syncthreads();
        // ---- stage A tile (128 x 32) ----
        if constexpr (A_BF) {
            const bf16* p = (const bf16*)A + (size_t)(m0 + sr) * lda + kb + sc;
            *(s16x8*)&sAh[sr * LS + sc]     = *(const s16x8*)p;
            *(s16x8*)&sAh[sr * LS + sc + 8] = *(const s16x8*)(p + 8);
        } else {
            const float* p = (const float*)A + (size_t)(m0 + sr) * lda + kb + sc;
            s16x8 h0, h1;
            if constexpr (A_SP) {
                s16x8 l0, l1;
                cvt8(p, h0, l0); cvt8(p + 8, h1, l1);
                *(s16x8*)&sAl[sr * LS + sc]     = l0;
                *(s16x8*)&sAl[sr * LS + sc + 8] = l1;
            } else {
                cvt8hi(p, h0); cvt8hi(p + 8, h1);
            }
            *(s16x8*)&sAh[sr * LS + sc]     = h0;
            *(s16x8*)&sAh[sr * LS + sc + 8] = h1;
        }
        // ---- stage B tile (128 x 32) ----
        if constexpr (B_BF) {
            const bf16* p = (const bf16*)Bt + (size_t)(n0 + sr) * ldb + kb + sc;
            *(s16x8*)&sBh[sr * LS + sc]     = *(const s16x8*)p;
            *(s16x8*)&sBh[sr * LS + sc + 8] = *(const s16x8*)(p + 8);
        } else {
            const float* p = (const float*)Bt + (size_t)(n0 + sr) * ldb + kb + sc;
            s16x8 h0, h1, l0, l1;
            cvt8(p, h0, l0); cvt8(p + 8, h1, l1);
            *(s16x8*)&sBh[sr * LS + sc]     = h0;
            *(s16x8*)&sBh[sr * LS + sc + 8] = h1;
            *(s16x8*)&sBl[sr * LS + sc]     = l0;
            *(s16x8*)&sBl[sr * LS + sc + 8] = l1;
        }
        __syncthreads();

        // ---- fragments + MFMA ----
        s16x8 ah[4], al[4], bh[4], bl[4];
        #pragma unroll
        for (int i = 0; i < 4; ++i) {
            const int ra = (wm * 64 + i * 16 + l16) * LS + l4 * 8;
            const int rb = (wn * 64 + i * 16 + l16) * LS + l4 * 8;
            ah[i] = *(const s16x8*)&sAh[ra];
            if constexpr (A_SP) al[i] = *(const s16x8*)&sAl[ra];
            bh[i] = *(const s16x8*)&sBh[rb];
            if constexpr (B_SP) bl[i] = *(const s16x8*)&sBl[rb];
        }
        #pragma unroll
        for (int mi = 0; mi < 4; ++mi)
            #pragma unroll
            for (int ni = 0; ni < 4; ++ni) {
                mfma_bf16(acc[mi][ni], ah[mi], bh[ni]);
                if constexpr (B_SP) mfma_bf16(acc[mi][ni], ah[mi], bl[ni]);
                if constexpr (A_SP) mfma_bf16(acc[mi][ni], al[mi], bh[ni]);
            }
    }

    // ---- epilogues (C frag: row = 4*l4 + r, col = l16) ----
    if constexpr (MODE == 0) {
        float* Q = (float*)Cbase;
        #pragma unroll
        for (int ni = 0; ni < 4; ++ni) {
            const int gn = n0 + wn * 64 + ni * 16 + l16;
            const float bs = bias[gn];
            const int h = gn >> 6, dk = gn & 63;
            #pragma unroll
            for (int mi = 0; mi < 4; ++mi) {
                const int gm0 = m0 + wm * 64 + mi * 16 + l4 * 4;
                const int b = gm0 >> 10, l0 = gm0 & 1023;
                float* dst = Q + (((size_t)(h * 8 + b)) * 1024 + l0) * 64 + dk;
                #pragma unroll
                for (int r = 0; r < 4; ++r) dst[(size_t)r * 64] = acc[mi][ni][r] + bs;
            }
        }
    } else if constexpr (MODE == 1) {
        bf16* Vt = (bf16*)Cbase;
        #pragma unroll
        for (int ni = 0; ni < 4; ++ni) {
            const int gn = n0 + wn * 64 + ni * 16 + l16;
            const float bs = bias[gn];
            const int h = gn >> 9, dv = gn & 511;
            #pragma unroll
            for (int mi = 0; mi < 4; ++mi) {
                const int gm0 = m0 + wm * 64 + mi * 16 + l4 * 4;
                const int b = gm0 >> 10, l0 = gm0 & 1023;
                ushort4 t;
                t.x = f2bfu(acc[mi][ni][0] + bs);
                t.y = f2bfu(acc[mi][ni][1] + bs);
                t.z = f2bfu(acc[mi][ni][2] + bs);
                t.w = f2bfu(acc[mi][ni][3] + bs);
                *(ushort4*)(Vt + ((size_t)(h * 8 + b) * 512 + dv) * 1024 + l0) = t;
            }
        }
    } else if constexpr (MODE == 2) {
        bf16* O = (bf16*)Cbase + (size_t)(aux * 8 + z) * 524288;
        #pragma unroll
        for (int mi = 0; mi < 4; ++mi) {
            const int gm0 = m0 + wm * 64 + mi * 16 + l4 * 4;
            #pragma unroll
            for (int ni = 0; ni < 4; ++ni) {
                const int gn = n0 + wn * 64 + ni * 16 + l16;
                #pragma unroll
                for (int r = 0; r < 4; ++r)
                    O[(size_t)(gm0 + r) * 512 + gn] = f2bf(acc[mi][ni][r]);
            }
        }
    } else if constexpr (MODE == 3) {
        bf16* G = (bf16*)Cbase + (size_t)z * 4194304;
        #pragma unroll
        for (int ni = 0; ni < 4; ++ni) {
            const int gn = n0 + wn * 64 + ni * 16 + l16;
            const float bs = bias[z * 512 + gn];
            #pragma unroll
            for (int mi = 0; mi < 4; ++mi) {
                const int gm0 = m0 + wm * 64 + mi * 16 + l4 * 4;
                #pragma unroll
                for (int r = 0; r < 4; ++r)
                    G[(size_t)(gm0 + r) * 512 + gn] = f2bf(acc[mi][ni][r] + bs);
            }
        }
    } else {
        float* Out = (float*)Cbase;
        #pragma unroll
        for (int mi = 0; mi < 4; ++mi) {
            const int gm0 = m0 + wm * 64 + mi * 16 + l4 * 4;
            const int len = lens[gm0 >> 10];
            #pragma unroll
            for (int ni = 0; ni < 4; ++ni) {
                const int gn = n0 + wn * 64 + ni * 16 + l16;
                const float bs = bias[gn];
                #pragma unroll
                for (int r = 0; r < 4; ++r) {
                    const int gm = gm0 + r;
                    const bool dead = (gm & 1023) >= len;
                    Out[(size_t)gm * 512 + gn] =
                        dead ? 0.f : acc[mi][ni][r] + bs + resid[(size_t)gm * 512 + gn];
                }
            }
        }
    }
}

// ---------------- f32: S = QK^T/8, masked softmax, P f32 (zero-padded) -----------------
// Round-4 proven math; inner loop restructured: per dj one K-read (f32x4) feeds
// 8 row-FMAs; per-lane dj-rotation removes the 8-way sK bank conflict.
__launch_bounds__(256)
__global__ void k_sattn_f32(const float* __restrict__ Qf, const float* __restrict__ Kf,
                            float* __restrict__ P, const int* __restrict__ lens, int head)
{
    __shared__ float S[32 * 1024];   // 128 KB
    __shared__ float sQ[32 * 68];
    __shared__ float sK[64 * 68];
    const int qb = blockIdx.x, z = blockIdx.y;      // z = batch
    const int hb = head * 8 + z;
    const int tid = threadIdx.x;

    {   // stage Q tile (32 x 64 f32)
        const int r = tid >> 3, d0 = (tid & 7) * 8;
        const float* src = &Qf[((size_t)hb * 1024 + (size_t)qb * 32 + r) * 64 + d0];
        *(f32x4*)&sQ[r * 68 + d0]     = *(const f32x4*)src;
        *(f32x4*)&sQ[r * 68 + d0 + 4] = *(const f32x4*)(src + 4);
    }

    const int k = tid & 63, qg = tid >> 6;          // wave qg owns rows [8qg, 8qg+8)
    const int rot = (k >> 3) * 2;                   // dj rotation: spreads banks
    for (int kc = 0; kc < 16; ++kc) {
        __syncthreads();             // protect sK overwrite (and first-iter sQ)
        {   // stage K chunk (64 x 64 f32)
            const int r = tid >> 2, c0 = (tid & 3) * 16;
            const float* src = &Kf[((size_t)hb * 1024 + (size_t)kc * 64 + r) * 64 + c0];
            #pragma unroll
            for (int c = 0; c < 4; ++c)
                *(f32x4*)&sK[r * 68 + c0 + c * 4] = *(const f32x4*)(src + c * 4);
        }
        __syncthreads();
        float a0 = 0.f, a1 = 0.f, a2 = 0.f, a3 = 0.f, a4 = 0.f, a5 = 0.f, a6 = 0.f, a7 = 0.f;
        #pragma unroll
        for (int djj = 0; djj < 16; ++djj) {
            const int dj = (djj + rot) & 15;
            const f32x4 kv = *(const f32x4*)&sK[k * 68 + dj * 4];
            const float* qb0 = &sQ[(qg * 8) * 68 + dj * 4];
            {
                const f32x4 qv = *(const f32x4*)(qb0 + 0 * 68);
                a0 += qv[0]*kv[0] + qv[1]*kv[1] + qv[2]*kv[2] + qv[3]*kv[3];
            }
            {
                const f32x4 qv = *(const f32x4*)(qb0 + 1 * 68);
                a1 += qv[0]*kv[0] + qv[1]*kv[1] + qv[2]*kv[2] + qv[3]*kv[3];
            }
            {
                const f32x4 qv = *(const f32x4*)(qb0 + 2 * 68);
                a2 += qv[0]*kv[0] + qv[1]*kv[1] + qv[2]*kv[2] + qv[3]*kv[3];
            }
            {
                const f32x4 qv = *(const f32x4*)(qb0 + 3 * 68);
                a3 += qv[0]*kv[0] + qv[1]*kv[1] + qv[2]*kv[2] + qv[3]*kv[3];
            }
            {
                const f32x4 qv = *(const f32x4*)(qb0 + 4 * 68);
                a4 += qv[0]*kv[0] + qv[1]*kv[1] + qv[2]*kv[2] + qv[3]*kv[3];
            }
            {
                const f32x4 qv = *(const f32x4*)(qb0 + 5 * 68);
                a5 += qv[0]*kv[0] + qv[1]*kv[1] + qv[2]*kv[2] + qv[3]*kv[3];
            }
            {
                const f32x4 qv = *(const f32x4*)(qb0 + 6 * 68);
                a6 += qv[0]*kv[0] + qv[1]*kv[1] + qv[2]*kv[2] + qv[3]*kv[3];
            }
            {
                const f32x4 qv = *(const f32x4*)(qb0 + 7 * 68);
                a7 += qv[0]*kv[0] + qv[1]*kv[1] + qv[2]*kv[2] + qv[3]*kv[3];
            }
        }
        const int sb = kc * 64 + k;
        S[(qg * 8 + 0) * 1024 + sb] = a0 * 0.125f;
        S[(qg * 8 + 1) * 1024 + sb] = a1 * 0.125f;
        S[(qg * 8 + 2) * 1024 + sb] = a2 * 0.125f;
        S[(qg * 8 + 3) * 1024 + sb] = a3 * 0.125f;
        S[(qg * 8 + 4) * 1024 + sb] = a4 * 0.125f;
        S[(qg * 8 + 5) * 1024 + sb] = a5 * 0.125f;
        S[(qg * 8 + 6) * 1024 + sb] = a6 * 0.125f;
        S[(qg * 8 + 7) * 1024 + sb] = a7 * 0.125f;
    }
    __syncthreads();

    const int len = lens[z], lenpad = lens[8 + z] * 32;
    const int w = tid >> 6, lane = tid & 63;
    for (int rr = 0; rr < 8; ++rr) {
        const int row = w * 8 + rr;
        float* Sr = &S[row * 1024];
        float mx = -3.0e38f;
        for (int j = lane; j < len; j += 64) mx = fmaxf(mx, Sr[j]);
        #pragma unroll
        for (int off = 32; off; off >>= 1) mx = fmaxf(mx, __shfl_xor(mx, off));
        float sum = 0.f;
        for (int j = lane; j < len; j += 64) { const float e = __expf(Sr[j] - mx); Sr[j] = e; sum += e; }
        #pragma unroll
        for (int off = 32; off; off >>= 1) sum += __shfl_xor(sum, off);
        const float rinv = 1.0f / sum;
        float* Pr = P + ((size_t)z * 1024 + (size_t)qb * 32 + row) * 1024;
        for (int j = lane; j < lenpad; j += 64)
            Pr[j] = (j < len) ? Sr[j] * rinv : 0.f;
    }
}

// ---------------- head-softmax gate combine: comb = sum_h softmax_h(G) * O -------------
__launch_bounds__(512)
__global__ void k_combine_f32(const bf16* __restrict__ G, const bf16* __restrict__ O,
                              float* __restrict__ comb)
{
    const size_t row = blockIdx.x;
    const int e = threadIdx.x;
    const size_t idx = row * 512 + e;
    float g[8];
    #pragma unroll
    for (int h = 0; h < 8; ++h) g[h] = bf2f(G[(size_t)h * 4194304 + idx]);
    float mx = g[0];
    #pragma unroll
    for (int h = 1; h < 8; ++h) mx = fmaxf(mx, g[h]);
    float s = 0.f, c = 0.f;
    #pragma unroll
    for (int h = 0; h < 8; ++h) {
        const float p = __expf(g[h] - mx);
        s += p;
        c += p * bf2f(O[(size_t)h * 4194304 + idx]);
    }
    comb[idx] = c / s;
}

__global__ void k_sentinel(float* out, int n) {
    const int i = blockIdx.x * 256 + threadIdx.x;
    if (i < n) out[i] = 12345.0f;
}

// ---------------------------------------------------------------------------------------
extern "C" void kernel_launch(void* const* d_in, const int* in_sizes, int n_in,
                              void* d_out, int out_size, void* d_ws, size_t ws_size,
                              hipStream_t stream)
{
    const float* enc = (const float*)d_in[0];
    const unsigned char* npm = (const unsigned char*)d_in[1];
    const float* wq  = (const float*)d_in[3];
    const float* bq  = (const float*)d_in[4];
    const float* wk  = (const float*)d_in[5];
    const float* bk  = (const float*)d_in[6];
    const float* wv  = (const float*)d_in[7];
    const float* bv  = (const float*)d_in[8];
    const float* wg  = (const float*)d_in[9];
    const float* bg  = (const float*)d_in[10];
    const float* wfc = (const float*)d_in[11];
    const float* bfc = (const float*)d_in[12];

    char* ws = (char*)d_ws;
    size_t o = 0;
    auto take = [&](size_t bytes) { char* p = ws + o; o += (bytes + 255) & ~(size_t)255; return p; };
    int*   lens = (int*)take(128);
    float* Qf   = (float*)take((size_t)4194304 * 4);   // [h][b][l][dk] f32
    float* Kf   = (float*)take((size_t)4194304 * 4);   // [h][b][l][dk] f32
    bf16*  Vt   = (bf16*)take((size_t)33554432 * 2);   // [h][b][dv][l] bf16; reused as G
    bf16*  Ob   = (bf16*)take((size_t)33554432 * 2);   // [h][b][l][dv] bf16
    float* Pf   = (float*)take((size_t)8388608 * 4);   // one head: [b][q][k] f32
    float* comb = (float*)take((size_t)4194304 * 4);   // [b,l][dv] f32
    bf16*  Gb   = Vt;

    if (ws_size < o) {
        k_sentinel<<<dim3((out_size + 255) / 256), 256, 0, stream>>>((float*)d_out, out_size);
        return;
    }

    k_lengths<<<1, 256, 0, stream>>>(npm, lens);

    // Q, K projections (MFMA, split-bf16 3-term); V projection (2-term)
    mgemm<0><<<dim3(64 * 4, 1), 256, 0, stream>>>(enc, wq, Qf, bq, nullptr, lens, 4, 0);
    mgemm<0><<<dim3(64 * 4, 1), 256, 0, stream>>>(enc, wk, Kf, bk, nullptr, lens, 4, 0);
    mgemm<1><<<dim3(64 * 32, 1), 256, 0, stream>>>(enc, wv, Vt, bv, nullptr, lens, 32, 0);

    // attention per head: f32 S+softmax -> P, then MFMA PV -> O
    for (int g = 0; g < 8; ++g) {
        k_sattn_f32<<<dim3(32, 8), 256, 0, stream>>>(Qf, Kf, Pf, lens, g);
        mgemm<2><<<dim3(8 * 4, 8), 256, 0, stream>>>(Pf, Vt + (size_t)g * 4194304, Ob,
                                                     nullptr, nullptr, lens, 4, g);
    }

    // gate GEMM per head (MFMA, A bf16-native, B split 2-term)
    mgemm<3><<<dim3(64 * 4, 8), 256, 0, stream>>>(Ob, wg, Gb, bg, nullptr, lens, 4, 0);

    // head softmax + weighted combine
    k_combine_f32<<<dim3(8192), 512, 0, stream>>>(Gb, Ob, comb);

    // FC + bias + residual + pad-mask -> f32 out
    mgemm<4><<<dim3(64 * 4, 1), 256, 0, stream>>>(comb, wfc, d_out, bfc, enc, lens, 4, 0);
}